// Round 2
// baseline (4860.555 us; speedup 1.0000x reference)
//
#include <hip/hip_runtime.h>
#include <hip/hip_bf16.h>
#include <hip/hip_fp16.h>
#include <cstdint>
#include <cstddef>

using bf16 = __hip_bfloat16;

constexpr int TS    = 1024;
constexpr int DIM   = 1024;
constexpr int DH    = 64;
constexpr int MEMN  = 1024;
constexpr int CMEMN = 256;
constexpr int KVN   = 2304;   // CMEM + MEM + T
constexpr int TMEM  = 1280;   // MEM + CMEM
constexpr int QT    = 8;      // q rows per attention block

__device__ __forceinline__ float bflo(uint32_t u){ return __uint_as_float(u << 16); }
__device__ __forceinline__ float bfhi(uint32_t u){ return __uint_as_float(u & 0xffff0000u); }
__device__ __forceinline__ float b2f(bf16 h){ return __bfloat162float(h); }

// ---------------- GEMM: C = A @ Bw^T (+bias). fp32 weights, fp32 acc. --------
// A: M x K row-major (fp32, or bf16 when ABF). Bw: N x K row-major fp32.
// C: M x N (bf16 when CBF, else fp32).
// mode 0: rows from Aptr. mode 1: rows gathered from [cmem | mem | x] per batch
// (a 64-row tile never spans a region boundary: 256, 1280, 2304 all mult. of 64).
template<int ABF, int CBF>
__global__ __launch_bounds__(256) void gemm_bt(
    const void* __restrict__ Aptr, const float* __restrict__ Bw,
    const float* __restrict__ bias, void* __restrict__ Cptr,
    int M, int N, int K, int mode,
    const float* __restrict__ g_cmem, const float* __restrict__ g_mem,
    const float* __restrict__ g_x)
{
    __shared__ float As[16][68];   // [k][m], stride 68 keeps rows 16B-aligned
    __shared__ float Bs[16][68];   // [k][n]
    const int tid = threadIdx.x;
    const int m0 = blockIdx.x * 64;
    const int n0 = blockIdx.y * 64;
    const int tx = tid & 15, ty = tid >> 4;
    const int arow = tid & 63;        // staged row (lane): conflict-free LDS writes
    const int acol = (tid >> 6) * 4;  // 4 contiguous k per thread (16B fp32 load)
    const float* Af = nullptr; const bf16* Ah = nullptr;
    if (ABF) {
        Ah = (const bf16*)Aptr + (size_t)m0 * K;
    } else if (mode == 0) {
        Af = (const float*)Aptr + (size_t)m0 * K;
    } else {
        int b = m0 / KVN, j = m0 % KVN;
        if (j < CMEMN)     Af = g_cmem + ((size_t)b*CMEMN + j) * (size_t)DIM;
        else if (j < TMEM) Af = g_mem  + ((size_t)b*MEMN + (j - CMEMN)) * (size_t)DIM;
        else               Af = g_x    + ((size_t)b*TS   + (j - TMEM)) * (size_t)DIM;
    }
    float acc[4][4] = {};
    for (int k0 = 0; k0 < K; k0 += 16) {
        float a4[4];
        if (ABF) {
            ushort4 u = *(const ushort4*)(Ah + (size_t)arow * K + (k0 + acol));
            a4[0] = __uint_as_float((uint32_t)u.x << 16);
            a4[1] = __uint_as_float((uint32_t)u.y << 16);
            a4[2] = __uint_as_float((uint32_t)u.z << 16);
            a4[3] = __uint_as_float((uint32_t)u.w << 16);
        } else {
            float4 v = *(const float4*)(Af + (size_t)arow * K + (k0 + acol));
            a4[0] = v.x; a4[1] = v.y; a4[2] = v.z; a4[3] = v.w;
        }
        float4 bv = *(const float4*)(Bw + (size_t)(n0 + arow) * K + (k0 + acol));
        __syncthreads();   // previous iteration's LDS reads done
        As[acol+0][arow] = a4[0]; As[acol+1][arow] = a4[1];
        As[acol+2][arow] = a4[2]; As[acol+3][arow] = a4[3];
        Bs[acol+0][arow] = bv.x;  Bs[acol+1][arow] = bv.y;
        Bs[acol+2][arow] = bv.z;  Bs[acol+3][arow] = bv.w;
        __syncthreads();
        #pragma unroll
        for (int kk = 0; kk < 16; ++kk) {
            float4 a4v = *(const float4*)&As[kk][ty*4];   // broadcast within wave
            float4 b4v = *(const float4*)&Bs[kk][tx*4];   // 2-way alias: free
            float a[4] = {a4v.x, a4v.y, a4v.z, a4v.w};
            float b[4] = {b4v.x, b4v.y, b4v.z, b4v.w};
            #pragma unroll
            for (int i = 0; i < 4; ++i)
                #pragma unroll
                for (int j = 0; j < 4; ++j)
                    acc[i][j] = fmaf(a[i], b[j], acc[i][j]);
        }
    }
    float bb[4] = {0.f, 0.f, 0.f, 0.f};
    if (bias) {
        #pragma unroll
        for (int j = 0; j < 4; ++j) bb[j] = bias[n0 + tx*4 + j];
    }
    #pragma unroll
    for (int i = 0; i < 4; ++i) {
        size_t row = (size_t)(m0 + ty*4 + i);
        if (CBF) {
            bf16* cp = (bf16*)Cptr + row * N + n0 + tx*4;
            #pragma unroll
            for (int j = 0; j < 4; ++j) cp[j] = __float2bfloat16(acc[i][j] + bb[j]);
        } else {
            float* cp = (float*)Cptr + row * N + n0 + tx*4;
            #pragma unroll
            for (int j = 0; j < 4; ++j) cp[j] = acc[i][j] + bb[j];
        }
    }
}

// ---------------- Attention ----------------
// score[r][k] = scale*(q_r . K_k + q_r . pe[k - qg + 1023]), causal-masked at
// k > qg + TMEM (pe index then >= KVN: exactly shift()'s zero region).
// Substituting u = k - r shares one pe row across the tile's 8 q rows.
// q, kv: bf16 intermediates. pe: fp32 input. out: bf16 intermediate.
__global__ __launch_bounds__(256) void attn(
    const bf16* __restrict__ q, const bf16* __restrict__ kvb,
    const float* __restrict__ pe, bf16* __restrict__ out)
{
    __shared__ alignas(16) __half sc[KVN * QT];     // scores, [k][r], 36.9 KB
    __shared__ alignas(16) float qs[QT][DH];
    __shared__ float po[4][QT][DH];
    __shared__ float wredm[4][QT];
    __shared__ float wredl[4][QT];
    __shared__ float rowinv[QT];
    const int tid  = threadIdx.x;
    const int lane = tid & 63, wid = tid >> 6;
    const int q0 = blockIdx.x * QT;
    const int bh = blockIdx.y;
    const int b = bh >> 4, h = bh & 15;
    const float scale = 0.125f;           // DH^-0.5
    const float NEGS = -60000.0f;         // representable in half; exp -> 0

    for (int idx = tid; idx < QT*DH; idx += 256) {
        int r = idx >> 6, d = idx & 63;
        qs[r][d] = b2f(q[((size_t)(b*TS + q0 + r)) * DIM + h*DH + d]);
    }
    __syncthreads();

    // phase 1a: q.K scores (one K row per thread-iter, 8 q rows from LDS)
    const bf16* Kbase = kvb + (size_t)b * KVN * 2048 + h * DH;
    for (int k = tid; k < KVN; k += 256) {
        const uint4* kr = (const uint4*)(Kbase + (size_t)k * 2048);
        float acc8[QT] = {};
        #pragma unroll
        for (int ch = 0; ch < 8; ++ch) {
            uint4 u = kr[ch];
            float k0 = bflo(u.x), k1 = bfhi(u.x), k2 = bflo(u.y), k3 = bfhi(u.y);
            float k4 = bflo(u.z), k5 = bfhi(u.z), k6 = bflo(u.w), k7 = bfhi(u.w);
            #pragma unroll
            for (int r = 0; r < QT; ++r) {
                const float4* qp = (const float4*)&qs[r][ch*8];
                float4 qa = qp[0], qb = qp[1];
                acc8[r] += qa.x*k0 + qa.y*k1 + qa.z*k2 + qa.w*k3
                         + qb.x*k4 + qb.y*k5 + qb.z*k6 + qb.w*k7;
            }
        }
        int kq = k - q0 - TMEM;           // masked iff kq > r
        uint32_t w4[4];
        #pragma unroll
        for (int p = 0; p < 4; ++p) {
            float s0 = (kq > 2*p    ) ? NEGS : scale * acc8[2*p];
            float s1 = (kq > 2*p + 1) ? NEGS : scale * acc8[2*p+1];
            uint32_t lo = __half_as_ushort(__float2half_rn(s0));
            uint32_t hi = __half_as_ushort(__float2half_rn(s1));
            w4[p] = lo | (hi << 16);
        }
        *(uint4*)&sc[(size_t)k * QT] = make_uint4(w4[0], w4[1], w4[2], w4[3]);
    }
    __syncthreads();

    // phase 1b: positional dots; pe row c = u - q0 + 1023 shared by rows r (k=u+r)
    const float* peH = pe + (size_t)h * KVN * DH;
    for (int u0 = (int)tid - 7; u0 < KVN; u0 += 256) {
        if (u0 > q0 + TMEM) break;        // pe index out of range == masked region
        int c = u0 - q0 + 1023;           // in [0, KVN) for all surviving u0
        const float4* pr = (const float4*)(peH + (size_t)c * DH);
        float acc8[QT] = {};
        #pragma unroll
        for (int ch = 0; ch < 16; ++ch) {
            float4 pv = pr[ch];
            #pragma unroll
            for (int r = 0; r < QT; ++r) {
                const float4* qp = (const float4*)&qs[r][ch*4];
                float4 qa = qp[0];
                acc8[r] += qa.x*pv.x + qa.y*pv.y + qa.z*pv.z + qa.w*pv.w;
            }
        }
        #pragma unroll
        for (int r = 0; r < QT; ++r) {
            int k = u0 + r;
            if (k >= 0 && k < KVN) {      // distinct (k,r) across threads: race-free
                int o = k * QT + r;
                sc[o] = __float2half_rn(__half2float(sc[o]) + scale * acc8[r]);
            }
        }
    }
    __syncthreads();

    // phase 2: softmax (max, exp, sum) per row; probs left unnormalized in sc
    float lm[QT];
    #pragma unroll
    for (int r = 0; r < QT; ++r) lm[r] = -3.0e38f;
    for (int k = tid; k < KVN; k += 256) {
        uint4 u = *(const uint4*)&sc[(size_t)k * QT];
        const __half* hp = (const __half*)&u;
        #pragma unroll
        for (int r = 0; r < QT; ++r) lm[r] = fmaxf(lm[r], __half2float(hp[r]));
    }
    #pragma unroll
    for (int r = 0; r < QT; ++r)
        for (int off = 32; off > 0; off >>= 1)
            lm[r] = fmaxf(lm[r], __shfl_xor(lm[r], off, 64));
    if (lane == 0) {
        #pragma unroll
        for (int r = 0; r < QT; ++r) wredm[wid][r] = lm[r];
    }
    __syncthreads();
    float m8[QT];
    #pragma unroll
    for (int r = 0; r < QT; ++r)
        m8[r] = fmaxf(fmaxf(wredm[0][r], wredm[1][r]), fmaxf(wredm[2][r], wredm[3][r]));
    float ls[QT] = {};
    for (int k = tid; k < KVN; k += 256) {
        uint4 u = *(uint4*)&sc[(size_t)k * QT];
        __half* hp = (__half*)&u;
        #pragma unroll
        for (int r = 0; r < QT; ++r) {
            float e = __expf(__half2float(hp[r]) - m8[r]);
            hp[r] = __float2half_rn(e);
            ls[r] += e;
        }
        *(uint4*)&sc[(size_t)k * QT] = u;
    }
    #pragma unroll
    for (int r = 0; r < QT; ++r)
        for (int off = 32; off > 0; off >>= 1)
            ls[r] += __shfl_xor(ls[r], off, 64);
    if (lane == 0) {
        #pragma unroll
        for (int r = 0; r < QT; ++r) wredl[wid][r] = ls[r];
    }
    __syncthreads();
    if (tid < QT)
        rowinv[tid] = 1.0f / (wredl[0][tid] + wredl[1][tid] + wredl[2][tid] + wredl[3][tid]);
    __syncthreads();

    // phase 3: O = P @ V. wave w owns a k-quarter; d = lane; probs via b128 broadcast
    const bf16* Vbase = kvb + (size_t)b * KVN * 2048 + 1024 + h * DH;
    float o8[QT] = {};
    const int kbeg = wid * (KVN/4), kend = kbeg + (KVN/4);
    for (int k = kbeg; k < kend; ++k) {
        uint4 u = *(const uint4*)&sc[(size_t)k * QT];
        const __half* hp = (const __half*)&u;
        float vv = b2f(Vbase[(size_t)k * 2048 + lane]);
        #pragma unroll
        for (int r = 0; r < QT; ++r) o8[r] = fmaf(__half2float(hp[r]), vv, o8[r]);
    }
    #pragma unroll
    for (int r = 0; r < QT; ++r) po[wid][r][lane] = o8[r];
    __syncthreads();
    for (int idx = tid; idx < QT*DH; idx += 256) {
        int r = idx >> 6, d = idx & 63;
        float s = po[0][r][d] + po[1][r][d] + po[2][r][d] + po[3][r][d];
        out[((size_t)(b*TS + q0 + r)) * DIM + h*DH + d] = __float2bfloat16(s * rowinv[r]);
    }
}

// new_mem = x (fp32 bit copy, 16 MB)
__global__ __launch_bounds__(256) void copy_u4(const uint4* __restrict__ src,
                                               uint4* __restrict__ dst, int n)
{
    int i = blockIdx.x * 256 + threadIdx.x;
    if (i < n) dst[i] = src[i];
}

// conv_w [o][i][r] -> cw2 [o][r][i]  (then conv == plain GEMM over k'=r*1024+i)
__global__ __launch_bounds__(256) void convw_transpose(const float* __restrict__ w,
                                                       float* __restrict__ w2)
{
    int idx = blockIdx.x * 256 + threadIdx.x;   // = o*4096 + r*1024 + i
    int o = idx >> 12, rem = idx & 4095, r = rem >> 10, i = rem & 1023;
    w2[idx] = w[(o << 12) + (i << 2) + r];
}

extern "C" void kernel_launch(void* const* d_in, const int* in_sizes, int n_in,
                              void* d_out, int out_size, void* d_ws, size_t ws_size,
                              hipStream_t stream)
{
    const float* x    = (const float*)d_in[0];
    const float* memp = (const float*)d_in[1];
    const float* cmem = (const float*)d_in[2];
    const float* pe   = (const float*)d_in[3];
    // d_in[4] input_mask: all ones; masking beyond causal is identity. Unused.
    const float* Wq   = (const float*)d_in[5];
    const float* Wkv  = (const float*)d_in[6];
    const float* Wout = (const float*)d_in[7];
    const float* bout = (const float*)d_in[8];
    const float* cw   = (const float*)d_in[9];
    const float* cb   = (const float*)d_in[10];
    float* outp = (float*)d_out;

    // Workspace layout (54.5 MB total):
    //   qb  (bf16, 8 MB)   at +0
    //   ao  (bf16, 8 MB)   at +8 MB
    //   kvb (bf16, 37.75)  at +16 MB   (k: cols 0..1023, v: 1024..2047)
    //   cw2 (fp32, 16 MB)  aliases [0, 16 MB) after qb & ao are dead
    char* wsb = (char*)d_ws;
    bf16*  qb  = (bf16*)(wsb);
    bf16*  ao  = (bf16*)(wsb + 8388608);
    bf16*  kvb = (bf16*)(wsb + 16777216);
    float* cw2 = (float*)(wsb);

    // q = x @ Wq^T  (bf16 out)
    gemm_bt<0,1><<<dim3(64, 16), 256, 0, stream>>>(x, Wq, nullptr, qb,
        4096, 1024, 1024, 0, nullptr, nullptr, nullptr);
    // kv = [cmem|mem|x] @ Wkv^T  (M = B*KV = 9216, N = 2048, bf16 out)
    gemm_bt<0,1><<<dim3(144, 32), 256, 0, stream>>>(nullptr, Wkv, nullptr, kvb,
        9216, 2048, 1024, 1, cmem, memp, x);
    // attention -> ao (bf16)
    attn<<<dim3(128, 64), 256, 0, stream>>>(qb, kvb, pe, ao);
    // logits = ao @ Wout^T + bout -> d_out[0 : 4.19M] (fp32)
    gemm_bt<1,0><<<dim3(64, 16), 256, 0, stream>>>(ao, Wout, bout, outp,
        4096, 1024, 1024, 0, nullptr, nullptr, nullptr);
    // new_mem = x -> d_out[4.19M : 8.39M]
    copy_u4<<<dim3(4096), 256, 0, stream>>>((const uint4*)x,
        (uint4*)(outp + 4194304), 1048576);
    // new_cmem = conv(mem) == mem(1024x4096) @ cw2(1024x4096)^T + cb
    convw_transpose<<<dim3(16384), 256, 0, stream>>>(cw, cw2);
    gemm_bt<0,0><<<dim3(16, 16), 256, 0, stream>>>(memp, cw2, cb, outp + 8388608,
        1024, 1024, 4096, 0, nullptr, nullptr, nullptr);
}

// Round 3
// 1457.035 us; speedup vs baseline: 3.3359x; 3.3359x over previous
//
#include <hip/hip_runtime.h>
#include <hip/hip_bf16.h>
#include <hip/hip_fp16.h>
#include <cstdint>
#include <cstddef>
#include <cstring>

using bf16 = __hip_bfloat16;

constexpr int TS    = 1024;
constexpr int DIM   = 1024;
constexpr int DH    = 64;
constexpr int MEMN  = 1024;
constexpr int CMEMN = 256;
constexpr int KVN   = 2304;   // CMEM + MEM + T
constexpr int TMEM  = 1280;   // MEM + CMEM

typedef __attribute__((ext_vector_type(8))) short short8;
typedef __attribute__((ext_vector_type(4))) float f32x4;

__device__ __forceinline__ float bflo(uint32_t u){ return __uint_as_float(u << 16); }
__device__ __forceinline__ float bfhi(uint32_t u){ return __uint_as_float(u & 0xffff0000u); }
__device__ __forceinline__ unsigned short f2bf_us(float f){
    __hip_bfloat16 t = __float2bfloat16(f);
    unsigned short us; memcpy(&us, &t, 2); return us;
}

// ---------------- GEMM: C = A @ Bw^T (+bias). fp32 weights, fp32 acc. --------
// (unchanged from R2 — known-good)
template<int ABF, int CBF>
__global__ __launch_bounds__(256) void gemm_bt(
    const void* __restrict__ Aptr, const float* __restrict__ Bw,
    const float* __restrict__ bias, void* __restrict__ Cptr,
    int M, int N, int K, int mode,
    const float* __restrict__ g_cmem, const float* __restrict__ g_mem,
    const float* __restrict__ g_x)
{
    __shared__ float As[16][68];
    __shared__ float Bs[16][68];
    const int tid = threadIdx.x;
    const int m0 = blockIdx.x * 64;
    const int n0 = blockIdx.y * 64;
    const int tx = tid & 15, ty = tid >> 4;
    const int arow = tid & 63;
    const int acol = (tid >> 6) * 4;
    const float* Af = nullptr; const bf16* Ah = nullptr;
    if (ABF) {
        Ah = (const bf16*)Aptr + (size_t)m0 * K;
    } else if (mode == 0) {
        Af = (const float*)Aptr + (size_t)m0 * K;
    } else {
        int b = m0 / KVN, j = m0 % KVN;
        if (j < CMEMN)     Af = g_cmem + ((size_t)b*CMEMN + j) * (size_t)DIM;
        else if (j < TMEM) Af = g_mem  + ((size_t)b*MEMN + (j - CMEMN)) * (size_t)DIM;
        else               Af = g_x    + ((size_t)b*TS   + (j - TMEM)) * (size_t)DIM;
    }
    float acc[4][4] = {};
    for (int k0 = 0; k0 < K; k0 += 16) {
        float a4[4];
        if (ABF) {
            ushort4 u = *(const ushort4*)(Ah + (size_t)arow * K + (k0 + acol));
            a4[0] = __uint_as_float((uint32_t)u.x << 16);
            a4[1] = __uint_as_float((uint32_t)u.y << 16);
            a4[2] = __uint_as_float((uint32_t)u.z << 16);
            a4[3] = __uint_as_float((uint32_t)u.w << 16);
        } else {
            float4 v = *(const float4*)(Af + (size_t)arow * K + (k0 + acol));
            a4[0] = v.x; a4[1] = v.y; a4[2] = v.z; a4[3] = v.w;
        }
        float4 bv = *(const float4*)(Bw + (size_t)(n0 + arow) * K + (k0 + acol));
        __syncthreads();
        As[acol+0][arow] = a4[0]; As[acol+1][arow] = a4[1];
        As[acol+2][arow] = a4[2]; As[acol+3][arow] = a4[3];
        Bs[acol+0][arow] = bv.x;  Bs[acol+1][arow] = bv.y;
        Bs[acol+2][arow] = bv.z;  Bs[acol+3][arow] = bv.w;
        __syncthreads();
        #pragma unroll
        for (int kk = 0; kk < 16; ++kk) {
            float4 a4v = *(const float4*)&As[kk][ty*4];
            float4 b4v = *(const float4*)&Bs[kk][tx*4];
            float a[4] = {a4v.x, a4v.y, a4v.z, a4v.w};
            float b[4] = {b4v.x, b4v.y, b4v.z, b4v.w};
            #pragma unroll
            for (int i = 0; i < 4; ++i)
                #pragma unroll
                for (int j = 0; j < 4; ++j)
                    acc[i][j] = fmaf(a[i], b[j], acc[i][j]);
        }
    }
    float bb[4] = {0.f, 0.f, 0.f, 0.f};
    if (bias) {
        #pragma unroll
        for (int j = 0; j < 4; ++j) bb[j] = bias[n0 + tx*4 + j];
    }
    #pragma unroll
    for (int i = 0; i < 4; ++i) {
        size_t row = (size_t)(m0 + ty*4 + i);
        if (CBF) {
            bf16* cp = (bf16*)Cptr + row * N + n0 + tx*4;
            #pragma unroll
            for (int j = 0; j < 4; ++j) cp[j] = __float2bfloat16(acc[i][j] + bb[j]);
        } else {
            float* cp = (float*)Cptr + row * N + n0 + tx*4;
            #pragma unroll
            for (int j = 0; j < 4; ++j) cp[j] = acc[i][j] + bb[j];
        }
    }
}

// ---------------- Flash attention with rel-pos, MFMA ----------------
// Per block: one (b,h), 64 q rows (4 waves x 16). Loop over 64-wide kv tiles:
//   S = Q@K^T (mfma), Spos via band mfma + in-quad shfl gather of
//   Ppos[i, j-i+1023], online softmax in C-layout regs, P@V via LDS C->A
//   round-trip. LDS tiles XOR-swizzled in 8-half chunks: addr(row,cc) =
//   row*64 + 8*((cc>>3)^(row&7)^((row>>3)&7)) + (cc&7)  -> balanced banks for
//   both row-contiguous b128 frag reads and the V-transpose scatter.
__device__ __forceinline__ short8 ldfrag(const unsigned short* base, int row, int chunk) {
    int ch = chunk ^ (row & 7) ^ ((row >> 3) & 7);
    return *(const short8*)(base + row*64 + ch*8);
}

__global__ __launch_bounds__(256) void attn(
    const bf16* __restrict__ qg, const bf16* __restrict__ kvb,
    const float* __restrict__ pe, bf16* __restrict__ out)
{
    __shared__ alignas(16) unsigned short Kt[64*64];
    __shared__ alignas(16) unsigned short Vt[64*64];     // transposed: Vt[d][j]
    __shared__ alignas(16) unsigned short PEb[144*64];
    __shared__ alignas(16) unsigned short Pb[64*64];     // Q at start, then P

    const int tid  = threadIdx.x;
    const int lane = tid & 63, w = tid >> 6;
    const int quad = lane >> 4, colq = lane & 15;

    // block swizzle: 4 batch-variants of one (h,q0) land on the same XCD slot
    const int L = blockIdx.x;
    const int b = (L >> 3) & 3;
    const int rest = (L & 7) | ((L >> 5) << 3);   // 0..255
    const int q0 = (rest & 15) * 64;
    const int h = rest >> 4;
    const float scale = 0.125f;

    const unsigned short* kvus = (const unsigned short*)kvb;

    // ---- stage Q tile (64x64) into Pb, extract per-wave A-frags ----
    for (int cid = tid; cid < 512; cid += 256) {
        int jr = cid >> 3, ch = cid & 7;
        uint4 v = *(const uint4*)((const unsigned short*)qg +
                    ((size_t)(b*TS + q0 + jr))*1024 + h*64 + ch*8);
        int ch2 = ch ^ (jr & 7) ^ ((jr >> 3) & 7);
        *(uint4*)(Pb + jr*64 + ch2*8) = v;
    }
    __syncthreads();
    short8 qa0 = ldfrag(Pb, 16*w + colq, quad);       // kk=0 chunks
    short8 qa1 = ldfrag(Pb, 16*w + colq, 4 + quad);   // kk=1 chunks

    float m_[4], l_[4];
    f32x4 oacc[4];
    #pragma unroll
    for (int r = 0; r < 4; ++r) { m_[r] = -1e30f; l_[r] = 0.f; }
    #pragma unroll
    for (int dt = 0; dt < 4; ++dt) oacc[dt] = (f32x4){0.f,0.f,0.f,0.f};

    const int nkv = min(36, ((q0 + 63 + TMEM) >> 6) + 1);
    const f32x4 zero4 = (f32x4){0.f,0.f,0.f,0.f};

    for (int kvt = 0; kvt < nkv; ++kvt) {
        const int kv0 = kvt * 64;
        __syncthreads();    // previous iteration's LDS reads (and Q-frag init) done

        // ---- stage K tile (rows as-is) ----
        for (int cid = tid; cid < 512; cid += 256) {
            int jr = cid >> 3, ch = cid & 7;
            uint4 v = *(const uint4*)(kvus +
                        ((size_t)(b*KVN + kv0 + jr))*2048 + h*64 + ch*8);
            int ch2 = ch ^ (jr & 7) ^ ((jr >> 3) & 7);
            *(uint4*)(Kt + jr*64 + ch2*8) = v;
        }
        // ---- stage V transposed: Vt[d][j] ----
        for (int cid = tid; cid < 512; cid += 256) {
            int jr = cid >> 3, ch = cid & 7;
            union { uint4 u; unsigned short us[8]; } U;
            U.u = *(const uint4*)(kvus +
                    ((size_t)(b*KVN + kv0 + jr))*2048 + 1024 + h*64 + ch*8);
            #pragma unroll
            for (int p = 0; p < 8; ++p) {
                int d = ch*8 + p;
                int ch2 = (jr >> 3) ^ (d & 7) ^ ((d >> 3) & 7);
                Vt[d*64 + ch2*8 + (jr & 7)] = U.us[p];
            }
        }
        // ---- stage pe band rows [cb, cb+144) (zero-filled outside [0,KVN)) ----
        const int cb = kv0 - q0 + 960;     // = kv0 - q0 - 63 + 1023
        for (int cid = tid; cid < 1152; cid += 256) {
            int rr = cid >> 3, ch = cid & 7;
            int c = cb + rr;
            unsigned short hv[8];
            if (c >= 0 && c < KVN) {
                const float* src = pe + ((size_t)h*KVN + c)*64 + ch*8;
                float4 f0 = *(const float4*)(src);
                float4 f1 = *(const float4*)(src + 4);
                hv[0]=f2bf_us(f0.x); hv[1]=f2bf_us(f0.y); hv[2]=f2bf_us(f0.z); hv[3]=f2bf_us(f0.w);
                hv[4]=f2bf_us(f1.x); hv[5]=f2bf_us(f1.y); hv[6]=f2bf_us(f1.z); hv[7]=f2bf_us(f1.w);
            } else {
                #pragma unroll
                for (int p = 0; p < 8; ++p) hv[p] = 0;
            }
            int ch2 = ch ^ (rr & 7) ^ ((rr >> 3) & 7);
            *(uint4*)(PEb + rr*64 + ch2*8) = *(const uint4*)hv;
        }
        __syncthreads();

        // ---- S = Q.K^T ----
        f32x4 facc[4];
        #pragma unroll
        for (int nt = 0; nt < 4; ++nt) {
            short8 b0 = ldfrag(Kt, nt*16 + colq, quad);
            short8 b1 = ldfrag(Kt, nt*16 + colq, 4 + quad);
            f32x4 t = __builtin_amdgcn_mfma_f32_16x16x32_bf16(qa0, b0, zero4, 0, 0, 0);
            facc[nt]  = __builtin_amdgcn_mfma_f32_16x16x32_bf16(qa1, b1, t, 0, 0, 0);
        }
        // ---- Ppos band: wave w uses staged rows [48-16w, 48-16w+80) ----
        f32x4 pacc[5];
        const int bandoff = 48 - 16*w;
        #pragma unroll
        for (int pnt = 0; pnt < 5; ++pnt) {
            int row = bandoff + pnt*16 + colq;
            short8 b0 = ldfrag(PEb, row, quad);
            short8 b1 = ldfrag(PEb, row, 4 + quad);
            f32x4 t = __builtin_amdgcn_mfma_f32_16x16x32_bf16(qa0, b0, zero4, 0, 0, 0);
            pacc[pnt] = __builtin_amdgcn_mfma_f32_16x16x32_bf16(qa1, b1, t, 0, 0, 0);
        }

        // ---- gather pos (in-quad shfl), mask, scale ----
        float s_[4][4];
        #pragma unroll
        for (int nt = 0; nt < 4; ++nt) {
            #pragma unroll
            for (int r = 0; r < 4; ++r) {
                int t = colq + 15 - 4*quad - r;          // band col - nt*16, in [0,30]
                int src = (lane & 48) | (t & 15);
                float g0 = __shfl(pacc[nt][r], src, 64);
                float g1 = __shfl(pacc[nt+1][r], src, 64);
                float g  = (t < 16) ? g0 : g1;
                float v  = (facc[nt][r] + g) * scale;
                int jg = kv0 + nt*16 + colq;
                int ig = q0 + 16*w + 4*quad + r;
                s_[nt][r] = (jg - ig > TMEM) ? -1e30f : v;
            }
        }

        // ---- online softmax + P write + PV ----
        #pragma unroll
        for (int r = 0; r < 4; ++r) {
            float tm = fmaxf(fmaxf(s_[0][r], s_[1][r]), fmaxf(s_[2][r], s_[3][r]));
            #pragma unroll
            for (int off = 1; off < 16; off <<= 1) tm = fmaxf(tm, __shfl_xor(tm, off, 64));
            float mn = fmaxf(m_[r], tm);
            float al = __expf(m_[r] - mn);
            m_[r] = mn;
            float ps[4], rs = 0.f;
            #pragma unroll
            for (int nt = 0; nt < 4; ++nt) { ps[nt] = __expf(s_[nt][r] - mn); rs += ps[nt]; }
            #pragma unroll
            for (int off = 1; off < 16; off <<= 1) rs += __shfl_xor(rs, off, 64);
            l_[r] = l_[r]*al + rs;
            #pragma unroll
            for (int dt = 0; dt < 4; ++dt) oacc[dt][r] *= al;
            int row = 16*w + 4*quad + r;
            #pragma unroll
            for (int nt = 0; nt < 4; ++nt) {
                int cc = nt*16 + colq;
                int ch2 = (cc >> 3) ^ (row & 7) ^ ((row >> 3) & 7);
                Pb[row*64 + ch2*8 + (cc & 7)] = f2bf_us(ps[nt]);
            }
        }
        // same-wave DS ordering makes Pb writes visible to this wave's reads
        short8 pa0 = ldfrag(Pb, 16*w + colq, quad);
        short8 pa1 = ldfrag(Pb, 16*w + colq, 4 + quad);
        #pragma unroll
        for (int dt = 0; dt < 4; ++dt) {
            short8 v0 = ldfrag(Vt, dt*16 + colq, quad);
            short8 v1 = ldfrag(Vt, dt*16 + colq, 4 + quad);
            f32x4 t = __builtin_amdgcn_mfma_f32_16x16x32_bf16(pa0, v0, oacc[dt], 0, 0, 0);
            oacc[dt]  = __builtin_amdgcn_mfma_f32_16x16x32_bf16(pa1, v1, t, 0, 0, 0);
        }
    }

    // ---- epilogue: normalize, store ----
    float inv[4];
    #pragma unroll
    for (int r = 0; r < 4; ++r) inv[r] = 1.0f / l_[r];
    #pragma unroll
    for (int dt = 0; dt < 4; ++dt) {
        #pragma unroll
        for (int r = 0; r < 4; ++r) {
            size_t row = (size_t)(b*TS + q0 + 16*w + 4*quad + r);
            out[row*1024 + h*64 + dt*16 + colq] = __float2bfloat16(oacc[dt][r] * inv[r]);
        }
    }
}

// new_mem = x (fp32 bit copy, 16 MB)
__global__ __launch_bounds__(256) void copy_u4(const uint4* __restrict__ src,
                                               uint4* __restrict__ dst, int n)
{
    int i = blockIdx.x * 256 + threadIdx.x;
    if (i < n) dst[i] = src[i];
}

// conv_w [o][i][r] -> cw2 [o][r][i]
__global__ __launch_bounds__(256) void convw_transpose(const float* __restrict__ w,
                                                       float* __restrict__ w2)
{
    int idx = blockIdx.x * 256 + threadIdx.x;
    int o = idx >> 12, rem = idx & 4095, r = rem >> 10, i = rem & 1023;
    w2[idx] = w[(o << 12) + (i << 2) + r];
}

extern "C" void kernel_launch(void* const* d_in, const int* in_sizes, int n_in,
                              void* d_out, int out_size, void* d_ws, size_t ws_size,
                              hipStream_t stream)
{
    const float* x    = (const float*)d_in[0];
    const float* memp = (const float*)d_in[1];
    const float* cmem = (const float*)d_in[2];
    const float* pe   = (const float*)d_in[3];
    const float* Wq   = (const float*)d_in[5];
    const float* Wkv  = (const float*)d_in[6];
    const float* Wout = (const float*)d_in[7];
    const float* bout = (const float*)d_in[8];
    const float* cw   = (const float*)d_in[9];
    const float* cb   = (const float*)d_in[10];
    float* outp = (float*)d_out;

    char* wsb = (char*)d_ws;
    bf16*  qb  = (bf16*)(wsb);
    bf16*  ao  = (bf16*)(wsb + 8388608);
    bf16*  kvb = (bf16*)(wsb + 16777216);
    float* cw2 = (float*)(wsb);           // aliases qb+ao after they're dead

    // q = x @ Wq^T  (bf16 out)
    gemm_bt<0,1><<<dim3(64, 16), 256, 0, stream>>>(x, Wq, nullptr, qb,
        4096, 1024, 1024, 0, nullptr, nullptr, nullptr);
    // kv = [cmem|mem|x] @ Wkv^T  (bf16 out)
    gemm_bt<0,1><<<dim3(144, 32), 256, 0, stream>>>(nullptr, Wkv, nullptr, kvb,
        9216, 2048, 1024, 1, cmem, memp, x);
    // flash attention -> ao (bf16)
    attn<<<dim3(1024), 256, 0, stream>>>(qb, kvb, pe, ao);
    // logits = ao @ Wout^T + bout -> d_out (fp32)
    gemm_bt<1,0><<<dim3(64, 16), 256, 0, stream>>>(ao, Wout, bout, outp,
        4096, 1024, 1024, 0, nullptr, nullptr, nullptr);
    // new_mem = x
    copy_u4<<<dim3(4096), 256, 0, stream>>>((const uint4*)x,
        (uint4*)(outp + 4194304), 1048576);
    // new_cmem = conv(mem) as GEMM
    convw_transpose<<<dim3(16384), 256, 0, stream>>>(cw, cw2);
    gemm_bt<0,0><<<dim3(16, 16), 256, 0, stream>>>(memp, cw2, cb, outp + 8388608,
        1024, 1024, 4096, 0, nullptr, nullptr, nullptr);
}

// Round 4
// 650.436 us; speedup vs baseline: 7.4728x; 2.2401x over previous
//
#include <hip/hip_runtime.h>
#include <hip/hip_bf16.h>
#include <hip/hip_fp16.h>
#include <cstdint>
#include <cstddef>
#include <cstring>

using bf16 = __hip_bfloat16;

constexpr int TS    = 1024;
constexpr int DIM   = 1024;
constexpr int DH    = 64;
constexpr int MEMN  = 1024;
constexpr int CMEMN = 256;
constexpr int KVN   = 2304;   // CMEM + MEM + T
constexpr int TMEM  = 1280;   // MEM + CMEM

typedef __attribute__((ext_vector_type(8))) short short8;
typedef __attribute__((ext_vector_type(4))) float f32x4;

__device__ __forceinline__ unsigned short f2bf_us(float f){
    __hip_bfloat16 t = __float2bfloat16(f);
    unsigned short us; memcpy(&us, &t, 2); return us;
}

// XOR-swizzled LDS tile (rows of 64 shorts, swizzle on 8-short chunks):
// slot(row, ch) = row*64 + 8*(ch ^ (row&7) ^ ((row>>3)&7)) + within-chunk
__device__ __forceinline__ short8 ldfrag(const unsigned short* base, int row, int chunk) {
    int ch = chunk ^ (row & 7) ^ ((row >> 3) & 7);
    return *(const short8*)(base + row*64 + ch*8);
}

__device__ __forceinline__ void gl2lds16(const void* g, void* l) {
    __builtin_amdgcn_global_load_lds(
        (const __attribute__((address_space(1))) void*)g,
        (__attribute__((address_space(3))) void*)l, 16, 0, 0);
}

// ---------------- pack: fp32 -> bf16 staging for all MFMA GEMM operands ------
// ranges (elements, 8 per thread):
//   [0, 9437184)          kvin  = [cmem|mem|x] per batch, rows of 1024
//   [9437184, 10485760)   wqb   = Wq
//   [10485760, 12582912)  wkvb  = Wkv
//   [12582912, 13631488)  woutb = Wout
//   [13631488, 17825792)  cw2b  = conv_w [o][i][r] -> [o][r*1024+i]
__global__ __launch_bounds__(256) void pack(
    const float* __restrict__ x, const float* __restrict__ memp,
    const float* __restrict__ cmem, const float* __restrict__ Wq,
    const float* __restrict__ Wkv, const float* __restrict__ Wout,
    const float* __restrict__ cw,
    unsigned short* __restrict__ kvin, unsigned short* __restrict__ wqb,
    unsigned short* __restrict__ wkvb, unsigned short* __restrict__ woutb,
    unsigned short* __restrict__ cw2b)
{
    const size_t t8 = ((size_t)blockIdx.x * 256 + threadIdx.x) * 8;
    unsigned short h[8];
    if (t8 < 9437184) {
        size_t g = t8 >> 10;
        int cc = (int)(t8 & 1023);
        int b = (int)(g / KVN), j = (int)(g % KVN);
        const float* src;
        if (j < CMEMN)      src = cmem + ((size_t)b*CMEMN + j)*1024 + cc;
        else if (j < TMEM)  src = memp + ((size_t)b*MEMN + (j - CMEMN))*1024 + cc;
        else                src = x    + ((size_t)b*TS   + (j - TMEM))*1024 + cc;
        float4 f0 = *(const float4*)src; float4 f1 = *(const float4*)(src + 4);
        h[0]=f2bf_us(f0.x); h[1]=f2bf_us(f0.y); h[2]=f2bf_us(f0.z); h[3]=f2bf_us(f0.w);
        h[4]=f2bf_us(f1.x); h[5]=f2bf_us(f1.y); h[6]=f2bf_us(f1.z); h[7]=f2bf_us(f1.w);
        *(uint4*)(kvin + t8) = *(const uint4*)h;
    } else if (t8 < 13631488) {
        const float* src; unsigned short* dst;
        if (t8 < 10485760)      { src = Wq   + (t8 - 9437184);  dst = wqb   + (t8 - 9437184); }
        else if (t8 < 12582912) { src = Wkv  + (t8 - 10485760); dst = wkvb  + (t8 - 10485760); }
        else                    { src = Wout + (t8 - 12582912); dst = woutb + (t8 - 12582912); }
        float4 f0 = *(const float4*)src; float4 f1 = *(const float4*)(src + 4);
        h[0]=f2bf_us(f0.x); h[1]=f2bf_us(f0.y); h[2]=f2bf_us(f0.z); h[3]=f2bf_us(f0.w);
        h[4]=f2bf_us(f1.x); h[5]=f2bf_us(f1.y); h[6]=f2bf_us(f1.z); h[7]=f2bf_us(f1.w);
        *(uint4*)dst = *(const uint4*)h;
    } else {
        size_t o8 = t8 - 13631488;
        int o = (int)(o8 >> 12); int rem = (int)(o8 & 4095);
        int r = rem >> 10, i = rem & 1023;
        #pragma unroll
        for (int p = 0; p < 8; ++p) h[p] = f2bf_us(cw[(o << 12) + (i + p)*4 + r]);
        *(uint4*)(cw2b + o8) = *(const uint4*)h;
    }
}

// ---------------- MFMA GEMM: C = A @ B^T (+bias) ----------------
// A: M x K bf16 (QMODE row mapping below), B: N x K bf16 row-major.
// 128x128 tile, BK=64; 4 waves in 2x2, each 64x64 via 4x4 mfma_16x16x32_bf16.
// Staging: global_load_lds 16B, source-chunk XOR swizzle -> conflict-free
// ds_read_b128 frag reads.
// QMODE 0: A rows contiguous. 1: x-region of kvin (m = b*1024+t).
//        2: mem-region of kvin reshaped (B*256 rows of 4096).
template<int CBF, int QMODE>
__global__ __launch_bounds__(256) void gemm_mfma(
    const bf16* __restrict__ Abf, const bf16* __restrict__ Bbf,
    const float* __restrict__ bias, void* __restrict__ Cptr,
    int M, int N, int K)
{
    __shared__ alignas(16) unsigned short As[128*64];
    __shared__ alignas(16) unsigned short Bs[128*64];
    const int tid = threadIdx.x, lane = tid & 63, w = tid >> 6;
    const int quad = lane >> 4, colq = lane & 15;
    const int wm = w >> 1, wn = w & 1;
    const int m0 = blockIdx.x * 128, n0 = blockIdx.y * 128;
    size_t abase;
    if (QMODE == 0)      abase = (size_t)m0 * K;
    else if (QMODE == 1) abase = ((size_t)((m0 >> 10)*KVN + TMEM + (m0 & 1023))) * 1024;
    else                 abase = ((size_t)((m0 >> 8)*KVN + CMEMN)) * 1024 + (size_t)(m0 & 255) * 4096;
    const unsigned short* Ag = (const unsigned short*)Abf + abase;
    const unsigned short* Bg = (const unsigned short*)Bbf + (size_t)n0 * K;

    const int srow0 = w*32 + (lane >> 3);
    const int sch2  = lane & 7;

    f32x4 acc[4][4];
    #pragma unroll
    for (int i = 0; i < 4; ++i)
        #pragma unroll
        for (int j = 0; j < 4; ++j) acc[i][j] = (f32x4){0.f,0.f,0.f,0.f};

    for (int k0 = 0; k0 < K; k0 += 64) {
        __syncthreads();   // previous iteration's frag reads complete
        #pragma unroll
        for (int c = 0; c < 4; ++c) {
            int rr = srow0 + c*8;
            int ch = sch2 ^ (rr & 7) ^ ((rr >> 3) & 7);
            gl2lds16(Ag + (size_t)rr*K + k0 + ch*8, &As[(w*32 + c*8)*64]);
            gl2lds16(Bg + (size_t)rr*K + k0 + ch*8, &Bs[(w*32 + c*8)*64]);
        }
        __syncthreads();   // drains vmcnt: staged data visible
        short8 af[4][2], bfr[4][2];
        #pragma unroll
        for (int i = 0; i < 4; ++i) {
            af[i][0]  = ldfrag(As, wm*64 + i*16 + colq, quad);
            af[i][1]  = ldfrag(As, wm*64 + i*16 + colq, 4 + quad);
            bfr[i][0] = ldfrag(Bs, wn*64 + i*16 + colq, quad);
            bfr[i][1] = ldfrag(Bs, wn*64 + i*16 + colq, 4 + quad);
        }
        #pragma unroll
        for (int i = 0; i < 4; ++i)
            #pragma unroll
            for (int j = 0; j < 4; ++j) {
                f32x4 t = __builtin_amdgcn_mfma_f32_16x16x32_bf16(af[i][0], bfr[j][0], acc[i][j], 0, 0, 0);
                acc[i][j] = __builtin_amdgcn_mfma_f32_16x16x32_bf16(af[i][1], bfr[j][1], t, 0, 0, 0);
            }
    }
    #pragma unroll
    for (int j = 0; j < 4; ++j) {
        int col = n0 + wn*64 + j*16 + colq;
        float bj = bias ? bias[col] : 0.0f;
        #pragma unroll
        for (int i = 0; i < 4; ++i) {
            #pragma unroll
            for (int r = 0; r < 4; ++r) {
                size_t row = (size_t)(m0 + wm*64 + i*16 + quad*4 + r);
                float v = acc[i][j][r] + bj;
                if (CBF) ((bf16*)Cptr)[row*N + col] = __float2bfloat16(v);
                else     ((float*)Cptr)[row*N + col] = v;
            }
        }
    }
}

// ---------------- Flash attention with rel-pos, MFMA (unchanged, R3-proven) --
__global__ __launch_bounds__(256) void attn(
    const bf16* __restrict__ qg, const bf16* __restrict__ kvb,
    const float* __restrict__ pe, bf16* __restrict__ out)
{
    __shared__ alignas(16) unsigned short Kt[64*64];
    __shared__ alignas(16) unsigned short Vt[64*64];
    __shared__ alignas(16) unsigned short PEb[144*64];
    __shared__ alignas(16) unsigned short Pb[64*64];

    const int tid  = threadIdx.x;
    const int lane = tid & 63, w = tid >> 6;
    const int quad = lane >> 4, colq = lane & 15;

    const int L = blockIdx.x;
    const int b = (L >> 3) & 3;
    const int rest = (L & 7) | ((L >> 5) << 3);
    const int q0 = (rest & 15) * 64;
    const int h = rest >> 4;
    const float scale = 0.125f;

    const unsigned short* kvus = (const unsigned short*)kvb;

    for (int cid = tid; cid < 512; cid += 256) {
        int jr = cid >> 3, ch = cid & 7;
        uint4 v = *(const uint4*)((const unsigned short*)qg +
                    ((size_t)(b*TS + q0 + jr))*1024 + h*64 + ch*8);
        int ch2 = ch ^ (jr & 7) ^ ((jr >> 3) & 7);
        *(uint4*)(Pb + jr*64 + ch2*8) = v;
    }
    __syncthreads();
    short8 qa0 = ldfrag(Pb, 16*w + colq, quad);
    short8 qa1 = ldfrag(Pb, 16*w + colq, 4 + quad);

    float m_[4], l_[4];
    f32x4 oacc[4];
    #pragma unroll
    for (int r = 0; r < 4; ++r) { m_[r] = -1e30f; l_[r] = 0.f; }
    #pragma unroll
    for (int dt = 0; dt < 4; ++dt) oacc[dt] = (f32x4){0.f,0.f,0.f,0.f};

    const int nkv = min(36, ((q0 + 63 + TMEM) >> 6) + 1);
    const f32x4 zero4 = (f32x4){0.f,0.f,0.f,0.f};

    for (int kvt = 0; kvt < nkv; ++kvt) {
        const int kv0 = kvt * 64;
        __syncthreads();

        for (int cid = tid; cid < 512; cid += 256) {
            int jr = cid >> 3, ch = cid & 7;
            uint4 v = *(const uint4*)(kvus +
                        ((size_t)(b*KVN + kv0 + jr))*2048 + h*64 + ch*8);
            int ch2 = ch ^ (jr & 7) ^ ((jr >> 3) & 7);
            *(uint4*)(Kt + jr*64 + ch2*8) = v;
        }
        for (int cid = tid; cid < 512; cid += 256) {
            int jr = cid >> 3, ch = cid & 7;
            union { uint4 u; unsigned short us[8]; } U;
            U.u = *(const uint4*)(kvus +
                    ((size_t)(b*KVN + kv0 + jr))*2048 + 1024 + h*64 + ch*8);
            #pragma unroll
            for (int p = 0; p < 8; ++p) {
                int d = ch*8 + p;
                int ch2 = (jr >> 3) ^ (d & 7) ^ ((d >> 3) & 7);
                Vt[d*64 + ch2*8 + (jr & 7)] = U.us[p];
            }
        }
        const int cb = kv0 - q0 + 960;
        for (int cid = tid; cid < 1152; cid += 256) {
            int rr = cid >> 3, ch = cid & 7;
            int c = cb + rr;
            unsigned short hv[8];
            if (c >= 0 && c < KVN) {
                const float* src = pe + ((size_t)h*KVN + c)*64 + ch*8;
                float4 f0 = *(const float4*)(src);
                float4 f1 = *(const float4*)(src + 4);
                hv[0]=f2bf_us(f0.x); hv[1]=f2bf_us(f0.y); hv[2]=f2bf_us(f0.z); hv[3]=f2bf_us(f0.w);
                hv[4]=f2bf_us(f1.x); hv[5]=f2bf_us(f1.y); hv[6]=f2bf_us(f1.z); hv[7]=f2bf_us(f1.w);
            } else {
                #pragma unroll
                for (int p = 0; p < 8; ++p) hv[p] = 0;
            }
            int ch2 = ch ^ (rr & 7) ^ ((rr >> 3) & 7);
            *(uint4*)(PEb + rr*64 + ch2*8) = *(const uint4*)hv;
        }
        __syncthreads();

        f32x4 facc[4];
        #pragma unroll
        for (int nt = 0; nt < 4; ++nt) {
            short8 b0 = ldfrag(Kt, nt*16 + colq, quad);
            short8 b1 = ldfrag(Kt, nt*16 + colq, 4 + quad);
            f32x4 t = __builtin_amdgcn_mfma_f32_16x16x32_bf16(qa0, b0, zero4, 0, 0, 0);
            facc[nt]  = __builtin_amdgcn_mfma_f32_16x16x32_bf16(qa1, b1, t, 0, 0, 0);
        }
        f32x4 pacc[5];
        const int bandoff = 48 - 16*w;
        #pragma unroll
        for (int pnt = 0; pnt < 5; ++pnt) {
            int row = bandoff + pnt*16 + colq;
            short8 b0 = ldfrag(PEb, row, quad);
            short8 b1 = ldfrag(PEb, row, 4 + quad);
            f32x4 t = __builtin_amdgcn_mfma_f32_16x16x32_bf16(qa0, b0, zero4, 0, 0, 0);
            pacc[pnt] = __builtin_amdgcn_mfma_f32_16x16x32_bf16(qa1, b1, t, 0, 0, 0);
        }

        float s_[4][4];
        #pragma unroll
        for (int nt = 0; nt < 4; ++nt) {
            #pragma unroll
            for (int r = 0; r < 4; ++r) {
                int t = colq + 15 - 4*quad - r;
                int src = (lane & 48) | (t & 15);
                float g0 = __shfl(pacc[nt][r], src, 64);
                float g1 = __shfl(pacc[nt+1][r], src, 64);
                float g  = (t < 16) ? g0 : g1;
                float v  = (facc[nt][r] + g) * scale;
                int jg = kv0 + nt*16 + colq;
                int ig = q0 + 16*w + 4*quad + r;
                s_[nt][r] = (jg - ig > TMEM) ? -1e30f : v;
            }
        }

        #pragma unroll
        for (int r = 0; r < 4; ++r) {
            float tm = fmaxf(fmaxf(s_[0][r], s_[1][r]), fmaxf(s_[2][r], s_[3][r]));
            #pragma unroll
            for (int off = 1; off < 16; off <<= 1) tm = fmaxf(tm, __shfl_xor(tm, off, 64));
            float mn = fmaxf(m_[r], tm);
            float al = __expf(m_[r] - mn);
            m_[r] = mn;
            float ps[4], rs = 0.f;
            #pragma unroll
            for (int nt = 0; nt < 4; ++nt) { ps[nt] = __expf(s_[nt][r] - mn); rs += ps[nt]; }
            #pragma unroll
            for (int off = 1; off < 16; off <<= 1) rs += __shfl_xor(rs, off, 64);
            l_[r] = l_[r]*al + rs;
            #pragma unroll
            for (int dt = 0; dt < 4; ++dt) oacc[dt][r] *= al;
            int row = 16*w + 4*quad + r;
            #pragma unroll
            for (int nt = 0; nt < 4; ++nt) {
                int cc = nt*16 + colq;
                int ch2 = (cc >> 3) ^ (row & 7) ^ ((row >> 3) & 7);
                Pb[row*64 + ch2*8 + (cc & 7)] = f2bf_us(ps[nt]);
            }
        }
        short8 pa0 = ldfrag(Pb, 16*w + colq, quad);
        short8 pa1 = ldfrag(Pb, 16*w + colq, 4 + quad);
        #pragma unroll
        for (int dt = 0; dt < 4; ++dt) {
            short8 v0 = ldfrag(Vt, dt*16 + colq, quad);
            short8 v1 = ldfrag(Vt, dt*16 + colq, 4 + quad);
            f32x4 t = __builtin_amdgcn_mfma_f32_16x16x32_bf16(pa0, v0, oacc[dt], 0, 0, 0);
            oacc[dt]  = __builtin_amdgcn_mfma_f32_16x16x32_bf16(pa1, v1, t, 0, 0, 0);
        }
    }

    float inv[4];
    #pragma unroll
    for (int r = 0; r < 4; ++r) inv[r] = 1.0f / l_[r];
    #pragma unroll
    for (int dt = 0; dt < 4; ++dt) {
        #pragma unroll
        for (int r = 0; r < 4; ++r) {
            size_t row = (size_t)(b*TS + q0 + 16*w + 4*quad + r);
            out[row*1024 + h*64 + dt*16 + colq] = __float2bfloat16(oacc[dt][r] * inv[r]);
        }
    }
}

// new_mem = x (fp32 bit copy, 16 MB)
__global__ __launch_bounds__(256) void copy_u4(const uint4* __restrict__ src,
                                               uint4* __restrict__ dst, int n)
{
    int i = blockIdx.x * 256 + threadIdx.x;
    if (i < n) dst[i] = src[i];
}

extern "C" void kernel_launch(void* const* d_in, const int* in_sizes, int n_in,
                              void* d_out, int out_size, void* d_ws, size_t ws_size,
                              hipStream_t stream)
{
    const float* x    = (const float*)d_in[0];
    const float* memp = (const float*)d_in[1];
    const float* cmem = (const float*)d_in[2];
    const float* pe   = (const float*)d_in[3];
    const float* Wq   = (const float*)d_in[5];
    const float* Wkv  = (const float*)d_in[6];
    const float* Wout = (const float*)d_in[7];
    const float* bout = (const float*)d_in[8];
    const float* cw   = (const float*)d_in[9];
    const float* cb   = (const float*)d_in[10];
    float* outp = (float*)d_out;

    // ws layout (bytes), total 90,177,536:
    char* wsb = (char*)d_ws;
    unsigned short* kvin  = (unsigned short*)(wsb);              // 18,874,368
    bf16*           kvb   = (bf16*)(wsb + 18874368);             // 37,748,736
    bf16*           qb    = (bf16*)(wsb + 56623104);             //  8,388,608
    bf16*           ao    = (bf16*)(wsb + 65011712);             //  8,388,608
    unsigned short* wqb   = (unsigned short*)(wsb + 73400320);   //  2,097,152
    unsigned short* wkvb  = (unsigned short*)(wsb + 75497472);   //  4,194,304
    unsigned short* woutb = (unsigned short*)(wsb + 79691776);   //  2,097,152
    unsigned short* cw2b  = (unsigned short*)(wsb + 81788928);   //  8,388,608

    // stage all bf16 operands
    pack<<<dim3(8704), 256, 0, stream>>>(x, memp, cmem, Wq, Wkv, Wout, cw,
        kvin, wqb, wkvb, woutb, cw2b);
    // q = x @ Wq^T  (A = kvin x-region)
    gemm_mfma<1,1><<<dim3(32, 8), 256, 0, stream>>>((const bf16*)kvin, (const bf16*)wqb,
        nullptr, qb, 4096, 1024, 1024);
    // kv = kvin @ Wkv^T
    gemm_mfma<1,0><<<dim3(72, 16), 256, 0, stream>>>((const bf16*)kvin, (const bf16*)wkvb,
        nullptr, kvb, 9216, 2048, 1024);
    // flash attention -> ao
    attn<<<dim3(1024), 256, 0, stream>>>(qb, kvb, pe, ao);
    // logits = ao @ Wout^T + bout -> d_out (fp32)
    gemm_mfma<0,0><<<dim3(32, 8), 256, 0, stream>>>(ao, (const bf16*)woutb,
        bout, outp, 4096, 1024, 1024);
    // new_mem = x
    copy_u4<<<dim3(4096), 256, 0, stream>>>((const uint4*)x,
        (uint4*)(outp + 4194304), 1048576);
    // new_cmem = conv(mem) as GEMM (A = kvin mem-region reshaped to 1024x4096)
    gemm_mfma<0,2><<<dim3(8, 8), 256, 0, stream>>>((const bf16*)kvin, (const bf16*)cw2b,
        cb, outp + 8388608, 1024, 1024, 4096);
}

// Round 5
// 558.859 us; speedup vs baseline: 8.6973x; 1.1639x over previous
//
#include <hip/hip_runtime.h>
#include <hip/hip_bf16.h>
#include <hip/hip_fp16.h>
#include <cstdint>
#include <cstddef>
#include <cstring>

using bf16 = __hip_bfloat16;

constexpr int TS    = 1024;
constexpr int DIM   = 1024;
constexpr int MEMN  = 1024;
constexpr int CMEMN = 256;
constexpr int KVN   = 2304;   // CMEM + MEM + T
constexpr int TMEM  = 1280;   // MEM + CMEM

typedef __attribute__((ext_vector_type(8))) short short8;
typedef __attribute__((ext_vector_type(4))) float f32x4;

__device__ __forceinline__ unsigned short f2bf_us(float f){
    __hip_bfloat16 t = __float2bfloat16(f);
    unsigned short us; memcpy(&us, &t, 2); return us;
}
__device__ __forceinline__ int sw8(int row){ return (row & 7) ^ ((row >> 3) & 7); }

// XOR-swizzled LDS tile (rows of 64 shorts, swizzle on 8-short chunks)
__device__ __forceinline__ short8 ldfrag(const unsigned short* base, int row, int chunk) {
    int ch = chunk ^ sw8(row);
    return *(const short8*)(base + row*64 + ch*8);
}
__device__ __forceinline__ void gl2lds16(const void* g, void* l) {
    __builtin_amdgcn_global_load_lds(
        (const __attribute__((address_space(1))) void*)g,
        (__attribute__((address_space(3))) void*)l, 16, 0, 0);
}

// ---------------- pack: fp32 -> bf16 staging ----------------
// [0, 9437184)           kvin = [cmem|mem|x] per batch (rows of 1024)
// [9437184, 10485760)    wqb  = Wq * 0.125 (exact pow2 scale)
// [10485760, 12582912)   wkvb = Wkv
// [12582912, 13631488)   woutb= Wout
// [13631488, 17825792)   cw2b = conv_w [o][i][r] -> [o][r*1024+i]
// [17825792, 20185088)   peb  = pos_emb bf16
__global__ __launch_bounds__(256) void pack(
    const float* __restrict__ x, const float* __restrict__ memp,
    const float* __restrict__ cmem, const float* __restrict__ Wq,
    const float* __restrict__ Wkv, const float* __restrict__ Wout,
    const float* __restrict__ cw, const float* __restrict__ pe,
    unsigned short* __restrict__ kvin, unsigned short* __restrict__ wqb,
    unsigned short* __restrict__ wkvb, unsigned short* __restrict__ woutb,
    unsigned short* __restrict__ cw2b, unsigned short* __restrict__ peb)
{
    const size_t t8 = ((size_t)blockIdx.x * 256 + threadIdx.x) * 8;
    unsigned short h[8];
    if (t8 < 9437184) {
        size_t g = t8 >> 10;
        int cc = (int)(t8 & 1023);
        int b = (int)(g / KVN), j = (int)(g % KVN);
        const float* src;
        if (j < CMEMN)      src = cmem + ((size_t)b*CMEMN + j)*1024 + cc;
        else if (j < TMEM)  src = memp + ((size_t)b*MEMN + (j - CMEMN))*1024 + cc;
        else                src = x    + ((size_t)b*TS   + (j - TMEM))*1024 + cc;
        float4 f0 = *(const float4*)src; float4 f1 = *(const float4*)(src + 4);
        h[0]=f2bf_us(f0.x); h[1]=f2bf_us(f0.y); h[2]=f2bf_us(f0.z); h[3]=f2bf_us(f0.w);
        h[4]=f2bf_us(f1.x); h[5]=f2bf_us(f1.y); h[6]=f2bf_us(f1.z); h[7]=f2bf_us(f1.w);
        *(uint4*)(kvin + t8) = *(const uint4*)h;
    } else if (t8 < 13631488) {
        const float* src; unsigned short* dst; float sc = 1.0f;
        if (t8 < 10485760)      { src = Wq   + (t8 - 9437184);  dst = wqb   + (t8 - 9437184); sc = 0.125f; }
        else if (t8 < 12582912) { src = Wkv  + (t8 - 10485760); dst = wkvb  + (t8 - 10485760); }
        else                    { src = Wout + (t8 - 12582912); dst = woutb + (t8 - 12582912); }
        float4 f0 = *(const float4*)src; float4 f1 = *(const float4*)(src + 4);
        h[0]=f2bf_us(f0.x*sc); h[1]=f2bf_us(f0.y*sc); h[2]=f2bf_us(f0.z*sc); h[3]=f2bf_us(f0.w*sc);
        h[4]=f2bf_us(f1.x*sc); h[5]=f2bf_us(f1.y*sc); h[6]=f2bf_us(f1.z*sc); h[7]=f2bf_us(f1.w*sc);
        *(uint4*)dst = *(const uint4*)h;
    } else if (t8 < 17825792) {
        size_t o8 = t8 - 13631488;
        int o = (int)(o8 >> 12); int rem = (int)(o8 & 4095);
        int r = rem >> 10, i = rem & 1023;
        #pragma unroll
        for (int p = 0; p < 8; ++p) h[p] = f2bf_us(cw[(o << 12) + (i + p)*4 + r]);
        *(uint4*)(cw2b + o8) = *(const uint4*)h;
    } else {
        size_t o8 = t8 - 17825792;
        const float* src = pe + o8;
        float4 f0 = *(const float4*)src; float4 f1 = *(const float4*)(src + 4);
        h[0]=f2bf_us(f0.x); h[1]=f2bf_us(f0.y); h[2]=f2bf_us(f0.z); h[3]=f2bf_us(f0.w);
        h[4]=f2bf_us(f1.x); h[5]=f2bf_us(f1.y); h[6]=f2bf_us(f1.z); h[7]=f2bf_us(f1.w);
        *(uint4*)(peb + o8) = *(const uint4*)h;
    }
}

// ---------------- MFMA GEMM: C = A @ B^T (+bias) ----------------
// 128x128 tile, BK=64, global_load_lds staging with source-chunk swizzle.
// EPI 0: fp32 out (+bias). 1: bf16 out. 2: kv split -> knat (K half, stride
//   1024) and Vh[((b*16+h)*64+d)*KVN + j] (V half, transposed, 8B stores).
// QMODE 0: A rows contiguous. 1: x-region of kvin. 2: mem-region as 1024x4096.
template<int EPI, int QMODE>
__global__ __launch_bounds__(256) void gemm_mfma(
    const bf16* __restrict__ Abf, const bf16* __restrict__ Bbf,
    const float* __restrict__ bias, void* __restrict__ Cptr,
    void* __restrict__ C2, int M, int N, int K)
{
    __shared__ alignas(16) unsigned short As[128*64];
    __shared__ alignas(16) unsigned short Bs[128*64];
    const int tid = threadIdx.x, lane = tid & 63, w = tid >> 6;
    const int quad = lane >> 4, colq = lane & 15;
    const int wm = w >> 1, wn = w & 1;
    const int m0 = blockIdx.x * 128, n0 = blockIdx.y * 128;
    size_t abase;
    if (QMODE == 0)      abase = (size_t)m0 * K;
    else if (QMODE == 1) abase = ((size_t)((m0 >> 10)*KVN + TMEM + (m0 & 1023))) * 1024;
    else                 abase = ((size_t)((m0 >> 8)*KVN + CMEMN)) * 1024 + (size_t)(m0 & 255) * 4096;
    const unsigned short* Ag = (const unsigned short*)Abf + abase;
    const unsigned short* Bg = (const unsigned short*)Bbf + (size_t)n0 * K;

    const int srow0 = w*32 + (lane >> 3);
    const int sch2  = lane & 7;

    f32x4 acc[4][4];
    #pragma unroll
    for (int i = 0; i < 4; ++i)
        #pragma unroll
        for (int j = 0; j < 4; ++j) acc[i][j] = (f32x4){0.f,0.f,0.f,0.f};

    for (int k0 = 0; k0 < K; k0 += 64) {
        __syncthreads();
        #pragma unroll
        for (int c = 0; c < 4; ++c) {
            int rr = srow0 + c*8;
            int ch = sch2 ^ sw8(rr);
            gl2lds16(Ag + (size_t)rr*K + k0 + ch*8, &As[(w*32 + c*8)*64]);
            gl2lds16(Bg + (size_t)rr*K + k0 + ch*8, &Bs[(w*32 + c*8)*64]);
        }
        __syncthreads();
        short8 af[4][2], bfr[4][2];
        #pragma unroll
        for (int i = 0; i < 4; ++i) {
            af[i][0]  = ldfrag(As, wm*64 + i*16 + colq, quad);
            af[i][1]  = ldfrag(As, wm*64 + i*16 + colq, 4 + quad);
            bfr[i][0] = ldfrag(Bs, wn*64 + i*16 + colq, quad);
            bfr[i][1] = ldfrag(Bs, wn*64 + i*16 + colq, 4 + quad);
        }
        #pragma unroll
        for (int i = 0; i < 4; ++i)
            #pragma unroll
            for (int j = 0; j < 4; ++j) {
                f32x4 t = __builtin_amdgcn_mfma_f32_16x16x32_bf16(af[i][0], bfr[j][0], acc[i][j], 0, 0, 0);
                acc[i][j] = __builtin_amdgcn_mfma_f32_16x16x32_bf16(af[i][1], bfr[j][1], t, 0, 0, 0);
            }
    }
    if (EPI == 2) {
        const int b = m0 / KVN;
        const int jj0 = (m0 - b*KVN) + wm*64;
        if (n0 < 1024) {            // K half -> knat [b*KVN + j][1024]
            bf16* kn = (bf16*)Cptr;
            #pragma unroll
            for (int j = 0; j < 4; ++j) {
                int col = n0 + wn*64 + j*16 + colq;
                #pragma unroll
                for (int i = 0; i < 4; ++i)
                    #pragma unroll
                    for (int r = 0; r < 4; ++r)
                        kn[(size_t)(b*KVN + jj0 + i*16 + quad*4 + r)*1024 + col] =
                            __float2bfloat16(acc[i][j][r]);
            }
        } else {                    // V half -> Vh [((b*16+h)*64+d)*KVN + j]
            unsigned short* vp = (unsigned short*)C2;
            #pragma unroll
            for (int j = 0; j < 4; ++j) {
                int col = n0 + wn*64 + j*16 + colq;
                int hh = (col >> 6) & 15, d = col & 63;
                #pragma unroll
                for (int i = 0; i < 4; ++i) {
                    int jjb = jj0 + i*16 + quad*4;
                    ushort4 u;
                    u.x = f2bf_us(acc[i][j][0]); u.y = f2bf_us(acc[i][j][1]);
                    u.z = f2bf_us(acc[i][j][2]); u.w = f2bf_us(acc[i][j][3]);
                    *(ushort4*)(vp + ((size_t)((b*16 + hh)*64 + d))*KVN + jjb) = u;
                }
            }
        }
    } else {
        #pragma unroll
        for (int j = 0; j < 4; ++j) {
            int col = n0 + wn*64 + j*16 + colq;
            float bj = bias ? bias[col] : 0.0f;
            #pragma unroll
            for (int i = 0; i < 4; ++i)
                #pragma unroll
                for (int r = 0; r < 4; ++r) {
                    size_t row = (size_t)(m0 + wm*64 + i*16 + quad*4 + r);
                    float v = acc[i][j][r] + bj;
                    if (EPI == 1) ((bf16*)Cptr)[row*N + col] = __float2bfloat16(v);
                    else          ((float*)Cptr)[row*N + col] = v;
                }
        }
    }
}

// ---------------- Flash attention, rel-pos, MFMA, DMA-staged ----------------
// Per block: (b,h), 128 q rows. Wave w owns rows [32w,32w+32) (2 it2 halves).
// Static-max softmax (q pre-scaled; scores bounded, exp(s) safe), l deferred.
// PEr: 256-row ring of pe rows (slot = c & 255); 64 new rows staged per tile.
__global__ __launch_bounds__(256) void attn(
    const unsigned short* __restrict__ qg,   // prescaled q bf16, [b*1024+i][1024]
    const unsigned short* __restrict__ kq,   // knat [b*KVN+j][1024]
    const unsigned short* __restrict__ vh,   // Vh [((b*16+h)*64+d)][KVN]
    const unsigned short* __restrict__ peb,  // [h][KVN][64] bf16
    bf16* __restrict__ out)                  // ao [b*1024+i][1024]
{
    __shared__ alignas(16) unsigned short Kt[64*64];    //  8 KB
    __shared__ alignas(16) unsigned short Vt[64*64];    //  8 KB  Vt[d][j]
    __shared__ alignas(16) unsigned short PEr[256*64];  // 32 KB ring
    __shared__ alignas(16) unsigned short Pb[128*64];   // 16 KB Q then P

    const int tid  = threadIdx.x;
    const int lane = tid & 63, w = tid >> 6;
    const int quad = lane >> 4, colq = lane & 15;
    const int jr = lane >> 3, l7 = lane & 7;

    const int bx = blockIdx.x;
    const int b = bx & 3, h = (bx >> 2) & 15, q0 = (bx >> 6) * 128;

    // ---- prologue: Q tile into Pb, pe prefill rows [896-q0, 1023-q0] ----
    #pragma unroll
    for (int c = 0; c < 4; ++c) {
        int row = c*32 + w*8 + jr;
        gl2lds16(qg + ((size_t)(b*1024 + q0 + row))*1024 + h*64 + (l7 ^ sw8(row))*8,
                 &Pb[(c*32 + w*8)*64]);
    }
    const int c0p = 896 - q0;
    #pragma unroll
    for (int c = 0; c < 4; ++c) {
        int cg = c0p + c*32 + w*8 + jr;
        int slot = cg & 255;
        gl2lds16(peb + ((size_t)h*KVN + cg)*64 + (l7 ^ sw8(slot))*8,
                 &PEr[((c0p + c*32 + w*8) & 255)*64]);
    }
    __syncthreads();
    short8 qa[2][2];
    #pragma unroll
    for (int it2 = 0; it2 < 2; ++it2) {
        qa[it2][0] = ldfrag(Pb, 32*w + 16*it2 + colq, quad);
        qa[it2][1] = ldfrag(Pb, 32*w + 16*it2 + colq, 4 + quad);
    }

    f32x4 oacc[2][4];
    float l_[2][4];
    #pragma unroll
    for (int it2 = 0; it2 < 2; ++it2) {
        #pragma unroll
        for (int dt = 0; dt < 4; ++dt) oacc[it2][dt] = (f32x4){0.f,0.f,0.f,0.f};
        #pragma unroll
        for (int r = 0; r < 4; ++r) l_[it2][r] = 0.f;
    }
    const f32x4 zero4 = (f32x4){0.f,0.f,0.f,0.f};
    const int nkv = min(36, ((q0 + 1407) >> 6) + 1);

    for (int kvt = 0; kvt < nkv; ++kvt) {
        const int kv0 = kvt * 64;
        __syncthreads();     // previous tile's LDS reads complete
        // K tile (rows j, cols d)
        #pragma unroll
        for (int c = 0; c < 2; ++c) {
            int row = c*32 + w*8 + jr;
            gl2lds16(kq + ((size_t)(b*KVN + kv0 + row))*1024 + h*64 + (l7 ^ sw8(row))*8,
                     &Kt[(c*32 + w*8)*64]);
        }
        // V tile transposed source (rows d, cols j)
        #pragma unroll
        for (int c = 0; c < 2; ++c) {
            int drow = c*32 + w*8 + jr;
            gl2lds16(vh + ((size_t)((b*16 + h)*64 + drow))*KVN + kv0 + (l7 ^ sw8(drow))*8,
                     &Vt[(c*32 + w*8)*64]);
        }
        // pe: 64 new ring rows [kv0-q0+1024, +1087], clamped (clamped rows only
        // feed causally-masked positions)
        const int cbase = kv0 - q0 + 1024;
        #pragma unroll
        for (int c = 0; c < 2; ++c) {
            int cg = cbase + c*32 + w*8 + jr;
            int cs = min(cg, KVN - 1);
            int slot = cg & 255;
            gl2lds16(peb + ((size_t)h*KVN + cs)*64 + (l7 ^ sw8(slot))*8,
                     &PEr[((cbase + c*32 + w*8) & 255)*64]);
        }
        __syncthreads();     // staged data visible

        short8 kf[4][2], vf[4][2];
        #pragma unroll
        for (int nt = 0; nt < 4; ++nt) {
            kf[nt][0] = ldfrag(Kt, nt*16 + colq, quad);
            kf[nt][1] = ldfrag(Kt, nt*16 + colq, 4 + quad);
            vf[nt][0] = ldfrag(Vt, nt*16 + colq, quad);
            vf[nt][1] = ldfrag(Vt, nt*16 + colq, 4 + quad);
        }

        #pragma unroll
        for (int it2 = 0; it2 < 2; ++it2) {
            // S = Q.K^T (pre-scaled)
            f32x4 facc[4];
            #pragma unroll
            for (int nt = 0; nt < 4; ++nt) {
                f32x4 t = __builtin_amdgcn_mfma_f32_16x16x32_bf16(qa[it2][0], kf[nt][0], zero4, 0, 0, 0);
                facc[nt] = __builtin_amdgcn_mfma_f32_16x16x32_bf16(qa[it2][1], kf[nt][1], t, 0, 0, 0);
            }
            // pos band: 5 tiles over ring rows [cb, cb+79]
            const int cb = kv0 - q0 + 1008 - 32*w - 16*it2;
            f32x4 pacc[5];
            #pragma unroll
            for (int pnt = 0; pnt < 5; ++pnt) {
                int slot = (cb + pnt*16 + colq) & 255;
                short8 b0 = ldfrag(PEr, slot, quad);
                short8 b1 = ldfrag(PEr, slot, 4 + quad);
                f32x4 t = __builtin_amdgcn_mfma_f32_16x16x32_bf16(qa[it2][0], b0, zero4, 0, 0, 0);
                pacc[pnt] = __builtin_amdgcn_mfma_f32_16x16x32_bf16(qa[it2][1], b1, t, 0, 0, 0);
            }
            // gather + exp + P write (no max-reduce: static-max softmax)
            const int prow0 = 32*w + 16*it2 + 4*quad;
            #pragma unroll
            for (int r = 0; r < 4; ++r) {
                int tt = colq + 15 - 4*quad - r;
                int src = (lane & 48) | (tt & 15);
                float sh[5];
                #pragma unroll
                for (int p = 0; p < 5; ++p) sh[p] = __shfl(pacc[p][r], src, 64);
                int ig = q0 + prow0 + r;
                float lsum = 0.f;
                float ps[4];
                #pragma unroll
                for (int nt = 0; nt < 4; ++nt) {
                    float g = (tt < 16) ? sh[nt] : sh[nt + 1];
                    float v = facc[nt][r] + g;
                    int jg = kv0 + nt*16 + colq;
                    float s = (jg - ig > TMEM) ? -1e30f : v;
                    ps[nt] = __expf(s);
                    lsum += ps[nt];
                }
                l_[it2][r] += lsum;
                int prow = prow0 + r;
                int swp = sw8(prow);
                #pragma unroll
                for (int nt = 0; nt < 4; ++nt) {
                    int cc = nt*16 + colq;
                    Pb[prow*64 + (((cc >> 3) ^ swp))*8 + (cc & 7)] = f2bf_us(ps[nt]);
                }
            }
            // PV (same-wave DS ordering: Pb writes visible to own reads)
            short8 pa0 = ldfrag(Pb, 32*w + 16*it2 + colq, quad);
            short8 pa1 = ldfrag(Pb, 32*w + 16*it2 + colq, 4 + quad);
            #pragma unroll
            for (int dt = 0; dt < 4; ++dt) {
                f32x4 t = __builtin_amdgcn_mfma_f32_16x16x32_bf16(pa0, vf[dt][0], oacc[it2][dt], 0, 0, 0);
                oacc[it2][dt] = __builtin_amdgcn_mfma_f32_16x16x32_bf16(pa1, vf[dt][1], t, 0, 0, 0);
            }
        }
    }

    // ---- epilogue: reduce l across 16 colq lanes, normalize, store ----
    #pragma unroll
    for (int it2 = 0; it2 < 2; ++it2) {
        #pragma unroll
        for (int r = 0; r < 4; ++r) {
            float lt = l_[it2][r];
            #pragma unroll
            for (int off = 1; off < 16; off <<= 1) lt += __shfl_xor(lt, off, 64);
            float inv = 1.0f / lt;
            size_t row = (size_t)(b*1024 + q0 + 32*w + 16*it2 + 4*quad + r);
            #pragma unroll
            for (int dt = 0; dt < 4; ++dt)
                out[row*1024 + h*64 + dt*16 + colq] = __float2bfloat16(oacc[it2][dt][r] * inv);
        }
    }
}

// new_mem = x (fp32 bit copy, 16 MB)
__global__ __launch_bounds__(256) void copy_u4(const uint4* __restrict__ src,
                                               uint4* __restrict__ dst, int n)
{
    int i = blockIdx.x * 256 + threadIdx.x;
    if (i < n) dst[i] = src[i];
}

extern "C" void kernel_launch(void* const* d_in, const int* in_sizes, int n_in,
                              void* d_out, int out_size, void* d_ws, size_t ws_size,
                              hipStream_t stream)
{
    const float* x    = (const float*)d_in[0];
    const float* memp = (const float*)d_in[1];
    const float* cmem = (const float*)d_in[2];
    const float* pe   = (const float*)d_in[3];
    const float* Wq   = (const float*)d_in[5];
    const float* Wkv  = (const float*)d_in[6];
    const float* Wout = (const float*)d_in[7];
    const float* bout = (const float*)d_in[8];
    const float* cw   = (const float*)d_in[9];
    const float* cb   = (const float*)d_in[10];
    float* outp = (float*)d_out;

    // ws layout (bytes), total ~94.9 MB
    char* wsb = (char*)d_ws;
    unsigned short* kvin  = (unsigned short*)(wsb);              // 18,874,368
    unsigned short* knat  = (unsigned short*)(wsb + 18874368);   // 18,874,368
    unsigned short* vhb   = (unsigned short*)(wsb + 37748736);   // 18,874,368
    unsigned short* qb    = (unsigned short*)(wsb + 56623104);   //  8,388,608
    bf16*           ao    = (bf16*)(wsb + 65011712);             //  8,388,608
    unsigned short* wqb   = (unsigned short*)(wsb + 73400320);   //  2,097,152
    unsigned short* wkvb  = (unsigned short*)(wsb + 75497472);   //  4,194,304
    unsigned short* woutb = (unsigned short*)(wsb + 79691776);   //  2,097,152
    unsigned short* cw2b  = (unsigned short*)(wsb + 81788928);   //  8,388,608
    unsigned short* peb   = (unsigned short*)(wsb + 90177536);   //  4,718,592

    // stage all bf16 operands (incl. prescaled Wq, bf16 pe)
    pack<<<dim3(9856), 256, 0, stream>>>(x, memp, cmem, Wq, Wkv, Wout, cw, pe,
        kvin, wqb, wkvb, woutb, cw2b, peb);
    // q = x @ (0.125*Wq)^T  (bf16, prescaled)
    gemm_mfma<1,1><<<dim3(32, 8), 256, 0, stream>>>((const bf16*)kvin, (const bf16*)wqb,
        nullptr, qb, nullptr, 4096, 1024, 1024);
    // kv = kvin @ Wkv^T -> K natural (knat), V transposed (vhb)
    gemm_mfma<2,0><<<dim3(72, 16), 256, 0, stream>>>((const bf16*)kvin, (const bf16*)wkvb,
        nullptr, knat, vhb, 9216, 2048, 1024);
    // flash attention -> ao
    attn<<<dim3(512), 256, 0, stream>>>(qb, knat, vhb, peb, ao);
    // logits = ao @ Wout^T + bout -> d_out (fp32)
    gemm_mfma<0,0><<<dim3(32, 8), 256, 0, stream>>>(ao, (const bf16*)woutb,
        bout, outp, nullptr, 4096, 1024, 1024);
    // new_mem = x
    copy_u4<<<dim3(4096), 256, 0, stream>>>((const uint4*)x,
        (uint4*)(outp + 4194304), 1048576);
    // new_cmem = conv(mem) as GEMM (mem-region of kvin as 1024x4096)
    gemm_mfma<0,2><<<dim3(8, 8), 256, 0, stream>>>((const bf16*)kvin, (const bf16*)cw2b,
        cb, outp + 8388608, nullptr, 1024, 1024, 4096);
}